// Round 1
// baseline (7878.487 us; speedup 1.0000x reference)
//
#include <hip/hip_runtime.h>
#include <cstddef>

namespace {

constexpr int B  = 128;
constexpr int T  = 256;
constexpr int HD = 512;
constexpr int G  = 2048;   // 4*HD gates
constexpr int TC = 32;     // time chunk for xg buffer
constexpr int XIN = 36;    // 32 real + 4 cat
constexpr int NCHUNK = T / TC;

__device__ __forceinline__ float sigmf(float x) { return 1.0f / (1.0f + expf(-x)); }
__device__ __forceinline__ float leakyf(float x) { return x >= 0.0f ? x : 0.1f * x; }

// ---------------- transpose Wh (512 x 2048) -> WhT[dir][2048][512] ----------------
__global__ void k_transpose(const float* __restrict__ Whf, const float* __restrict__ Whr,
                            float* __restrict__ WhT) {
  __shared__ float tile[32][33];
  const int d = blockIdx.z;
  const float* src = d ? Whr : Whf;
  const int j0 = blockIdx.x * 32, k0 = blockIdx.y * 32;
  for (int i = threadIdx.y; i < 32; i += 8)
    tile[i][threadIdx.x] = src[(size_t)(k0 + i) * G + j0 + threadIdx.x];
  __syncthreads();
  for (int i = threadIdx.y; i < 32; i += 8)
    WhT[((size_t)d * G + j0 + i) * HD + k0 + threadIdx.x] = tile[threadIdx.x][i];
}

__global__ void k_out_init(float* __restrict__ out, const float* __restrict__ b3) {
  const int i = blockIdx.x * 256 + threadIdx.x;
  if (i < B * T) out[i] = b3[0];
}

// ---------------- K1: embed-gather + GEMM (M=B*T, K=64, N=512) + leaky ----------------
__global__ void k_embed_gemm1(const float* __restrict__ x0, const float* __restrict__ emb,
                              const float* __restrict__ W1, const float* __restrict__ b1,
                              float* __restrict__ x1) {
  __shared__ float As[64][65];
  __shared__ float Bs[64][68];
  const int tid = threadIdx.x;
  const int m0 = blockIdx.x * 64, n0 = blockIdx.y * 64;

  for (int i = tid; i < 64 * 64; i += 256) {
    const int m = i >> 6, k = i & 63;
    const size_t row = (size_t)(m0 + m);
    float v;
    if (k < 32) {
      v = x0[row * XIN + k];
    } else {
      const int c = (k - 32) >> 3, e = (k - 32) & 7;
      const int idx = (int)x0[row * XIN + 32 + c];
      v = emb[(size_t)(c * 100 + idx) * 8 + e];
    }
    As[m][k] = v;
  }
  for (int j = 0; j < 4; ++j) {
    const int q = tid + 256 * j;
    const int kk = q >> 4, nq = q & 15;
    *(float4*)&Bs[kk][nq * 4] = *(const float4*)&W1[(size_t)kk * HD + n0 + nq * 4];
  }
  __syncthreads();

  const int ty = tid >> 4, tx = tid & 15;
  float acc[4][4] = {};
  #pragma unroll 8
  for (int k = 0; k < 64; ++k) {
    const float a0 = As[ty * 4 + 0][k], a1 = As[ty * 4 + 1][k];
    const float a2 = As[ty * 4 + 2][k], a3 = As[ty * 4 + 3][k];
    const float4 bv = *(const float4*)&Bs[k][tx * 4];
    acc[0][0] += a0 * bv.x; acc[0][1] += a0 * bv.y; acc[0][2] += a0 * bv.z; acc[0][3] += a0 * bv.w;
    acc[1][0] += a1 * bv.x; acc[1][1] += a1 * bv.y; acc[1][2] += a1 * bv.z; acc[1][3] += a1 * bv.w;
    acc[2][0] += a2 * bv.x; acc[2][1] += a2 * bv.y; acc[2][2] += a2 * bv.z; acc[2][3] += a2 * bv.w;
    acc[3][0] += a3 * bv.x; acc[3][1] += a3 * bv.y; acc[3][2] += a3 * bv.z; acc[3][3] += a3 * bv.w;
  }
  const float4 b4 = *(const float4*)&b1[n0 + tx * 4];
  for (int i = 0; i < 4; ++i) {
    float4 o;
    o.x = leakyf(acc[i][0] + b4.x);
    o.y = leakyf(acc[i][1] + b4.y);
    o.z = leakyf(acc[i][2] + b4.z);
    o.w = leakyf(acc[i][3] + b4.w);
    *(float4*)&x1[(size_t)(m0 + ty * 4 + i) * HD + n0 + tx * 4] = o;
  }
}

// ---------------- K2: GEMM (M=B*T, K=512, N=512) + leaky. Tile 128x64, KC=32, 8x4/thread --------
__global__ void k_gemm2(const float* __restrict__ x1, const float* __restrict__ W2,
                        const float* __restrict__ b2, float* __restrict__ x2) {
  __shared__ float As[128][36];
  __shared__ float Bs[32][68];
  const int tid = threadIdx.x;
  const int m0 = blockIdx.x * 128, n0 = blockIdx.y * 64;
  const int ty = tid >> 4, tx = tid & 15;
  float acc[8][4] = {};

  for (int k0 = 0; k0 < HD; k0 += 32) {
    __syncthreads();
    #pragma unroll
    for (int j = 0; j < 4; ++j) {
      const int q = tid + 256 * j;
      const int m = q >> 3, kq = q & 7;
      *(float4*)&As[m][kq * 4] = *(const float4*)&x1[(size_t)(m0 + m) * HD + k0 + kq * 4];
    }
    #pragma unroll
    for (int j = 0; j < 2; ++j) {
      const int q = tid + 256 * j;
      const int kk = q >> 4, nq = q & 15;
      *(float4*)&Bs[kk][nq * 4] = *(const float4*)&W2[(size_t)(k0 + kk) * HD + n0 + nq * 4];
    }
    __syncthreads();
    #pragma unroll 8
    for (int k = 0; k < 32; ++k) {
      const float4 bv = *(const float4*)&Bs[k][tx * 4];
      #pragma unroll
      for (int i = 0; i < 8; ++i) {
        const float a = As[ty * 8 + i][k];
        acc[i][0] += a * bv.x; acc[i][1] += a * bv.y; acc[i][2] += a * bv.z; acc[i][3] += a * bv.w;
      }
    }
  }
  const float4 b4 = *(const float4*)&b2[n0 + tx * 4];
  for (int i = 0; i < 8; ++i) {
    float4 o;
    o.x = leakyf(acc[i][0] + b4.x);
    o.y = leakyf(acc[i][1] + b4.y);
    o.z = leakyf(acc[i][2] + b4.z);
    o.w = leakyf(acc[i][3] + b4.w);
    *(float4*)&x2[(size_t)(m0 + ty * 8 + i) * HD + n0 + tx * 4] = o;
  }
}

// ---------------- K3: xg chunk GEMM: (TC*B x 512) @ Wi (512x2048) + bi + bh --------------------
// xg[dir][tc][b][gc]; A row (dir,tc,b) = x2[b][ dir? T-1-(c0+tc) : c0+tc ]
__global__ void k_gemm_xg(const float* __restrict__ x2,
                          const float* __restrict__ Wif, const float* __restrict__ Wir,
                          const float* __restrict__ bif, const float* __restrict__ bhf,
                          const float* __restrict__ bir, const float* __restrict__ bhr,
                          float* __restrict__ xg, int c0) {
  __shared__ float As[128][36];
  __shared__ float Bs[32][68];
  const int dir = blockIdx.z;
  const float* Wi = dir ? Wir : Wif;
  const float* bi = dir ? bir : bif;
  const float* bh = dir ? bhr : bhf;
  const int tid = threadIdx.x;
  const int m0 = blockIdx.x * 128, n0 = blockIdx.y * 64;
  const int ty = tid >> 4, tx = tid & 15;
  float acc[8][4] = {};

  for (int k0 = 0; k0 < HD; k0 += 32) {
    __syncthreads();
    #pragma unroll
    for (int j = 0; j < 4; ++j) {
      const int q = tid + 256 * j;
      const int m = q >> 3, kq = q & 7;
      const int r = m0 + m;
      const int b = r & (B - 1);
      const int t = c0 + (r >> 7);
      const int tg = dir ? (T - 1 - t) : t;
      *(float4*)&As[m][kq * 4] = *(const float4*)&x2[((size_t)b * T + tg) * HD + k0 + kq * 4];
    }
    #pragma unroll
    for (int j = 0; j < 2; ++j) {
      const int q = tid + 256 * j;
      const int kk = q >> 4, nq = q & 15;
      *(float4*)&Bs[kk][nq * 4] = *(const float4*)&Wi[(size_t)(k0 + kk) * G + n0 + nq * 4];
    }
    __syncthreads();
    #pragma unroll 8
    for (int k = 0; k < 32; ++k) {
      const float4 bv = *(const float4*)&Bs[k][tx * 4];
      #pragma unroll
      for (int i = 0; i < 8; ++i) {
        const float a = As[ty * 8 + i][k];
        acc[i][0] += a * bv.x; acc[i][1] += a * bv.y; acc[i][2] += a * bv.z; acc[i][3] += a * bv.w;
      }
    }
  }
  const int nb = n0 + tx * 4;
  float4 bias;
  bias.x = bi[nb + 0] + bh[nb + 0];
  bias.y = bi[nb + 1] + bh[nb + 1];
  bias.z = bi[nb + 2] + bh[nb + 2];
  bias.w = bi[nb + 3] + bh[nb + 3];
  for (int i = 0; i < 8; ++i) {
    const int r = m0 + ty * 8 + i;   // = tc*B + b
    float4 o;
    o.x = acc[i][0] + bias.x;
    o.y = acc[i][1] + bias.y;
    o.z = acc[i][2] + bias.z;
    o.w = acc[i][3] + bias.w;
    *(float4*)&xg[((size_t)dir * TC * B + r) * G + nb] = o;
  }
}

// ---------------- K4: one LSTM step, both directions ----------------
// grid 256 = dir(2) x bt(8, 16 batches) x jt(16, 32 hidden)
// block 256: gcl = tid&63 (gate cols gcl, gcl+64 of the 128-col tile), sub=tid>>6: kh=sub>>1, bg=sub&1
__global__ __launch_bounds__(256) void k_scan_step(
    const float* __restrict__ xg, const float* __restrict__ WhT,
    float* __restrict__ cbuf, float* __restrict__ hbuf,
    float* __restrict__ out, const float* __restrict__ W3, int t) {
  __shared__ float hT[16][516];          // [local b][k], stride 516 for aligned f4 + bank spread
  __shared__ float wlds[2][128][68];     // [kh][local gate col][k-in-chunk]
  __shared__ float red[128][17];
  __shared__ float gl[128][17];
  __shared__ float rbuf[16][17];

  const int tid = threadIdx.x;
  const int bid = blockIdx.x;
  const int dir = bid >> 7;
  const int bt  = (bid >> 4) & 7;
  const int jt  = bid & 15;

  const int gcl = tid & 63;
  const int sub = tid >> 6;
  const int kh  = sub >> 1;
  const int bg  = sub & 1;
  const int bloc0 = bg * 8;

  // stage h (prev step) transposed-by-row into LDS; zeros at t==0
  {
    const int bl = tid & 15, kseg = tid >> 4;
    const size_t hsrc = (((size_t)(t & 1) * 2 + dir) * B + (bt * 16 + bl)) * HD;
    for (int i = 0; i < 8; ++i) {
      const int k = kseg * 32 + i * 4;
      float4 v;
      if (t == 0) { v.x = 0.f; v.y = 0.f; v.z = 0.f; v.w = 0.f; }
      else v = *(const float4*)&hbuf[hsrc + k];
      *(float4*)&hT[bl][k] = v;
    }
  }

  float acc0[8] = {}, acc1[8] = {};
  const size_t wbase = (size_t)dir * G * HD;

  for (int kk = 0; kk < 4; ++kk) {
    __syncthreads();
    // stage weight chunk: 2 kh-halves x 128 cols x 64 k
    #pragma unroll
    for (int i = 0; i < 16; ++i) {
      const int f4 = tid + 256 * i;
      const int rloc = f4 >> 4;
      const int kq = f4 & 15;
      const int khr = rloc >> 7;
      const int gcr = rloc & 127;
      const int gcol = (gcr >> 5) * HD + jt * 32 + (gcr & 31);
      const int kg = khr * 256 + kk * 64 + kq * 4;
      *(float4*)&wlds[khr][gcr][kq * 4] =
          *(const float4*)&WhT[wbase + (size_t)gcol * HD + kg];
    }
    __syncthreads();
    const int kbase = kh * 256 + kk * 64;
    #pragma unroll 4
    for (int kq = 0; kq < 16; ++kq) {
      const float4 w0 = *(const float4*)&wlds[kh][gcl][kq * 4];
      const float4 w1 = *(const float4*)&wlds[kh][64 + gcl][kq * 4];
      #pragma unroll
      for (int b = 0; b < 8; ++b) {
        const float4 hv = *(const float4*)&hT[bloc0 + b][kbase + kq * 4];
        acc0[b] += hv.x * w0.x + hv.y * w0.y + hv.z * w0.z + hv.w * w0.w;
        acc1[b] += hv.x * w1.x + hv.y * w1.y + hv.z * w1.z + hv.w * w1.w;
      }
    }
  }

  __syncthreads();
  const int lane2 = bg * 64 + gcl;
  if (kh == 1) {
    #pragma unroll
    for (int b = 0; b < 8; ++b) { red[lane2][b] = acc0[b]; red[lane2][8 + b] = acc1[b]; }
  }
  __syncthreads();
  if (kh == 0) {
    #pragma unroll
    for (int b = 0; b < 8; ++b) {
      gl[gcl][bloc0 + b]      = acc0[b] + red[lane2][b];
      gl[64 + gcl][bloc0 + b] = acc1[b] + red[lane2][8 + b];
    }
  }
  __syncthreads();

  // gate nonlinearity, c/h update, W3 partial
  const int bl = tid & 15;
  const int bglob = bt * 16 + bl;
  const int tc = t & (TC - 1);
  const float* xgrow = xg + (((size_t)dir * TC + tc) * B + bglob) * G;
  float contrib = 0.0f;
  #pragma unroll
  for (int pp = 0; pp < 2; ++pp) {
    const int jloc = (tid >> 4) + pp * 16;   // 0..31
    const int jglob = jt * 32 + jloc;
    const float gf = gl[jloc][bl]      + xgrow[jglob];
    const float gi = gl[32 + jloc][bl] + xgrow[HD + jglob];
    const float ga = gl[64 + jloc][bl] + xgrow[2 * HD + jglob];
    const float go = gl[96 + jloc][bl] + xgrow[3 * HD + jglob];
    const size_t cidx = ((size_t)dir * B + bglob) * HD + jglob;
    const float cold = (t == 0) ? 0.0f : cbuf[cidx];
    const float cn = sigmf(gf) * cold + sigmf(gi) * tanhf(ga);
    const float hn = sigmf(go) * tanhf(cn);
    cbuf[cidx] = cn;
    hbuf[(((size_t)((t + 1) & 1) * 2 + dir) * B + bglob) * HD + jglob] = hn;
    contrib += hn * W3[dir * HD + jglob];
  }
  rbuf[tid >> 4][bl] = contrib;
  __syncthreads();
  if (tid < 16) {
    float s = 0.0f;
    #pragma unroll
    for (int m = 0; m < 16; ++m) s += rbuf[m][tid];
    atomicAdd(&out[(size_t)(bt * 16 + tid) * T + t], s);
  }
}

}  // namespace

extern "C" void kernel_launch(void* const* d_in, const int* in_sizes, int n_in,
                              void* d_out, int out_size, void* d_ws, size_t ws_size,
                              hipStream_t stream) {
  const float* x0   = (const float*)d_in[0];
  const float* emb  = (const float*)d_in[1];
  const float* W1   = (const float*)d_in[2];
  const float* b1   = (const float*)d_in[3];
  const float* W2   = (const float*)d_in[4];
  const float* b2   = (const float*)d_in[5];
  const float* Wi_f = (const float*)d_in[6];
  const float* bi_f = (const float*)d_in[7];
  const float* Wh_f = (const float*)d_in[8];
  const float* bh_f = (const float*)d_in[9];
  const float* Wi_r = (const float*)d_in[10];
  const float* bi_r = (const float*)d_in[11];
  const float* Wh_r = (const float*)d_in[12];
  const float* bh_r = (const float*)d_in[13];
  const float* W3   = (const float*)d_in[14];
  const float* b3   = (const float*)d_in[15];
  float* out = (float*)d_out;

  // workspace layout (floats): total 36,044,800 floats = 137.5 MiB
  float* ws   = (float*)d_ws;
  float* bufA = ws;                         // 16,777,216: x1, then xg chunks
  float* x2   = bufA + (size_t)16777216;    // 16,777,216
  float* WhT  = x2   + (size_t)16777216;    //  2,097,152
  float* hbuf = WhT  + (size_t)2097152;     //    262,144 (2 slots x 2 dirs x B x HD)
  float* cbuf = hbuf + (size_t)262144;      //    131,072 (2 dirs x B x HD)

  k_transpose<<<dim3(G / 32, HD / 32, 2), dim3(32, 8), 0, stream>>>(Wh_f, Wh_r, WhT);
  k_out_init<<<dim3((B * T + 255) / 256), 256, 0, stream>>>(out, b3);
  k_embed_gemm1<<<dim3(B * T / 64, HD / 64), 256, 0, stream>>>(x0, emb, W1, b1, bufA);
  k_gemm2<<<dim3(B * T / 128, HD / 64), 256, 0, stream>>>(bufA, W2, b2, x2);

  for (int c = 0; c < NCHUNK; ++c) {
    k_gemm_xg<<<dim3(TC * B / 128, G / 64, 2), 256, 0, stream>>>(
        x2, Wi_f, Wi_r, bi_f, bh_f, bi_r, bh_r, bufA, c * TC);
    for (int tt = 0; tt < TC; ++tt) {
      const int t = c * TC + tt;
      k_scan_step<<<dim3(256), 256, 0, stream>>>(bufA, WhT, cbuf, hbuf, out, W3, t);
    }
  }
}